// Round 1
// baseline (419.143 us; speedup 1.0000x reference)
//
#include <hip/hip_runtime.h>

#define DIM 128
#define MOMENTUM 0.5f

// One wave (64 lanes) per row. Each lane owns 2 consecutive floats (float2).
// Row source values are read from `out` (which already holds a copy of
// `memory` via the preceding D2D memcpy on the same stream).
__global__ void FeatureBank_update_rows(const float* __restrict__ x,
                                        const int* __restrict__ y,
                                        float* __restrict__ out,
                                        int batch) {
    const int lane = threadIdx.x & 63;
    const int wave = threadIdx.x >> 6;
    const int row = blockIdx.x * (blockDim.x >> 6) + wave;
    if (row >= batch) return;

    const long long dst = (long long)y[row] * DIM;

    const float2 xv = ((const float2*)(x + (long long)row * DIM))[lane];
    const float2 mv = ((const float2*)(out + dst))[lane];

    float2 w;
    w.x = MOMENTUM * mv.x + (1.0f - MOMENTUM) * xv.x;
    w.y = MOMENTUM * mv.y + (1.0f - MOMENTUM) * xv.y;

    float ss = w.x * w.x + w.y * w.y;
    // wave64 butterfly reduction
    #pragma unroll
    for (int off = 32; off > 0; off >>= 1)
        ss += __shfl_xor(ss, off, 64);

    const float inv = rsqrtf(ss);
    float2 o;
    o.x = w.x * inv;
    o.y = w.y * inv;
    ((float2*)(out + dst))[lane] = o;
}

extern "C" void kernel_launch(void* const* d_in, const int* in_sizes, int n_in,
                              void* d_out, int out_size, void* d_ws, size_t ws_size,
                              hipStream_t stream) {
    const float* x      = (const float*)d_in[0];
    const int*   y      = (const int*)d_in[1];
    const float* memory = (const float*)d_in[2];
    float*       out    = (float*)d_out;

    const int batch = in_sizes[1];              // 4096
    const size_t bytes = (size_t)out_size * sizeof(float);  // 500000*128*4

    // Bulk copy memory -> out (stream-ordered, graph-capture safe).
    hipMemcpyAsync(out, memory, bytes, hipMemcpyDeviceToDevice, stream);

    // Update the touched rows in place.
    const int waves_per_block = 4;              // 256 threads
    const int block = 64 * waves_per_block;
    const int grid = (batch + waves_per_block - 1) / waves_per_block;
    FeatureBank_update_rows<<<grid, block, 0, stream>>>(x, y, out, batch);
}